// Round 9
// baseline (273.706 us; speedup 1.0000x reference)
//
#include <hip/hip_runtime.h>
#include <math.h>

typedef float f32x4 __attribute__((ext_vector_type(4)));

// Problem constants: B=64, H=2048, NH=8, HD=256
constexpr int Bb  = 64;
constexpr int Hh  = 2048;
constexpr int NHh = 8;
constexpr int HDd = 256;

// Output flat offsets (c_new, n_new, m_new, h_norm), all f32
constexpr size_t C_OFF = 0;
constexpr size_t N_OFF = (size_t)Bb * NHh * HDd * HDd;            // 33554432
constexpr size_t M_OFF = N_OFF + (size_t)Bb * NHh * HDd;          // 33685504
constexpr size_t H_OFF = M_OFF + (size_t)Bb * NHh;                // 33686016

// ws layout (floats): [0 .. 2047]  gates: per (b,h) {f', i', m_new, denom}
//                     [4096 .. ]   nom partials: (tile*4+s)*256
constexpr size_t PS = 4096;

// ---------------------------------------------------------------------------
// Kernel A (64 blocks x 256): gates + n_new + denominator.
// ---------------------------------------------------------------------------
__global__ __launch_bounds__(256) void gates_kernel(
    const float* __restrict__ q, const float* __restrict__ k,
    const float* __restrict__ v, const float* __restrict__ n_in,
    const float* __restrict__ m_in,
    const float* __restrict__ wi_k, const float* __restrict__ wi_b,
    const float* __restrict__ wf_k, const float* __restrict__ wf_b,
    float* __restrict__ ws, float* __restrict__ out)
{
    const int b    = blockIdx.x;
    const int t    = threadIdx.x;
    const int lane = t & 63;
    const int wv   = t >> 6;

    float ai[8], af[8];
#pragma unroll
    for (int i = 0; i < 8; ++i) { ai[i] = 0.f; af[i] = 0.f; }

#pragma unroll 4
    for (int j = 0; j < 24; ++j) {
        const int r = t + 256 * j;
        float x;
        if (r < Hh)            x = q[b * Hh + r];
        else if (r < 2 * Hh)   x = k[b * Hh + r - Hh];
        else                   x = v[b * Hh + r - 2 * Hh];

        const f32x4 wa = *(const f32x4*)(wi_k + (size_t)r * 8);
        const f32x4 wb = *(const f32x4*)(wi_k + (size_t)r * 8 + 4);
        ai[0] = fmaf(x, wa[0], ai[0]); ai[1] = fmaf(x, wa[1], ai[1]);
        ai[2] = fmaf(x, wa[2], ai[2]); ai[3] = fmaf(x, wa[3], ai[3]);
        ai[4] = fmaf(x, wb[0], ai[4]); ai[5] = fmaf(x, wb[1], ai[5]);
        ai[6] = fmaf(x, wb[2], ai[6]); ai[7] = fmaf(x, wb[3], ai[7]);

        const f32x4 fa = *(const f32x4*)(wf_k + (size_t)r * 8);
        const f32x4 fb = *(const f32x4*)(wf_k + (size_t)r * 8 + 4);
        af[0] = fmaf(x, fa[0], af[0]); af[1] = fmaf(x, fa[1], af[1]);
        af[2] = fmaf(x, fa[2], af[2]); af[3] = fmaf(x, fa[3], af[3]);
        af[4] = fmaf(x, fb[0], af[4]); af[5] = fmaf(x, fb[1], af[5]);
        af[6] = fmaf(x, fb[2], af[6]); af[7] = fmaf(x, fb[3], af[7]);
    }

#pragma unroll
    for (int i = 0; i < 8; ++i) {
#pragma unroll
        for (int o = 32; o > 0; o >>= 1) {
            ai[i] += __shfl_down(ai[i], o, 64);
            af[i] += __shfl_down(af[i], o, 64);
        }
    }

    __shared__ float s_part[4][16];
    __shared__ float s_g[8][3];     // f', i', m_new per head
    if (lane == 0) {
#pragma unroll
        for (int i = 0; i < 8; ++i) {
            s_part[wv][i]     = ai[i];
            s_part[wv][8 + i] = af[i];
        }
    }
    __syncthreads();

    if (t < 8) {
        const int h = t;
        const float it = s_part[0][h] + s_part[1][h] + s_part[2][h] + s_part[3][h]
                         + wi_b[h];
        const float ft = s_part[0][8 + h] + s_part[1][8 + h] + s_part[2][8 + h]
                         + s_part[3][8 + h] + wf_b[h];
        const float logf_ = -(fmaxf(-ft, 0.f) + log1pf(expf(-fabsf(ft))));
        const float m_old = m_in[b * NHh + h];
        const float m_new = fmaxf(logf_ + m_old, it);
        const float fp    = expf(logf_ + m_old - m_new);
        const float ip    = expf(it - m_new);
        const int blk = b * NHh + h;
        s_g[h][0] = fp; s_g[h][1] = ip; s_g[h][2] = m_new;
        ws[blk * 4 + 0] = fp;
        ws[blk * 4 + 1] = ip;
        ws[blk * 4 + 2] = m_new;
        out[M_OFF + blk] = m_new;
    }
    __syncthreads();

    // n_new (8 heads x 256) + per-head denominator dot
    float pd[8];
#pragma unroll
    for (int h = 0; h < 8; ++h) {
        const float kv = k[b * Hh + h * HDd + t] * 0.0625f;   // 1/sqrt(256)
        const float nn = fmaf(s_g[h][0], n_in[((size_t)b * 8 + h) * HDd + t],
                              s_g[h][1] * kv);
        out[N_OFF + ((size_t)b * 8 + h) * HDd + t] = nn;
        pd[h] = q[b * Hh + h * HDd + t] * nn;
    }
#pragma unroll
    for (int h = 0; h < 8; ++h)
#pragma unroll
        for (int o = 32; o > 0; o >>= 1) pd[h] += __shfl_down(pd[h], o, 64);

    __shared__ float s_dp[4][8];
    if (lane == 0) {
#pragma unroll
        for (int h = 0; h < 8; ++h) s_dp[wv][h] = pd[h];
    }
    __syncthreads();
    if (t < 8) {
        const float dd = s_dp[0][t] + s_dp[1][t] + s_dp[2][t] + s_dp[3][t];
        ws[(b * 8 + t) * 4 + 3] = fmaxf(fabsf(dd), expf(-s_g[t][2])) + 1e-6f;
    }
}

// ---------------------------------------------------------------------------
// Kernel B (2048 blocks x 256): c-stream. Block = 64-row stripe of one (b,h)
// tile; wave wv owns local rows [wv*16, wv*16+16); lane owns float4-column.
// KEY: all 16 loads are issued BEFORE any store. The ordering fence is an
// asm memory clobber — binding at IR *and* MIR level (sched_barrier was
// bypassed by IR passes sinking readonly loads: VGPR_Count 56 < 64 proved
// the 16 loads were never all live). With loads older than every store,
// in-order vmcnt retirement means no cv[j] wait ever gates on a store.
// ---------------------------------------------------------------------------
__global__ __launch_bounds__(256) void stream_kernel(
    const float* __restrict__ q, const float* __restrict__ k,
    const float* __restrict__ v, const float* __restrict__ c_in,
    const float* __restrict__ ws_r, float* __restrict__ ws_w,
    float* __restrict__ out)
{
    const int blk  = blockIdx.x;
    const int tile = blk >> 2;      // b*8 + h
    const int s    = blk & 3;       // stripe of 64 rows
    const int b    = tile >> 3;
    const int h    = tile & 7;
    const int t    = threadIdx.x;
    const int lane = t & 63;
    const int wv   = t >> 6;

    __shared__ float s_kh[64];
    __shared__ float s_qh[64];
    __shared__ f32x4 s_nom[4][64];

    if (t < 64) {
        const int r = s * 64 + t;   // global row staged at local slot t
        s_kh[t] = k[b * Hh + h * HDd + r] * 0.0625f;
        s_qh[t] = q[b * Hh + h * HDd + r];
    }
    const float fp  = ws_r[tile * 4 + 0];
    const float ip  = ws_r[tile * 4 + 1];
    const f32x4 vh4 = ((const f32x4*)(v + b * Hh + h * HDd))[lane];
    __syncthreads();

    const size_t cbase = (size_t)tile * (HDd * HDd);
    const f32x4* cin   = (const f32x4*)(c_in + cbase);
    f32x4*       cout  = (f32x4*)(out + C_OFF + cbase);
    const int    l0    = wv * 16;          // local row base
    const int    g0    = s * 64 + l0;      // global row base

    // Phase 1: issue ALL 16 loads, keep them live in registers.
    f32x4 cv[16];
#pragma unroll
    for (int j = 0; j < 16; ++j)
        cv[j] = cin[(g0 + j) * 64 + lane];

    // Hard fence: asm may read/write any memory, so no load may sink below
    // and no store may hoist above. Enforced at IR and machine level.
    asm volatile("" ::: "memory");

    // Phase 2: compute + store (all stores younger than all loads).
    f32x4 nom = {0.f, 0.f, 0.f, 0.f};
#pragma unroll
    for (int j = 0; j < 16; ++j) {
        const int   lr = l0 + j;            // local row (LDS index)
        const f32x4 cn = fp * cv[j] + (ip * s_kh[lr]) * vh4;
        __builtin_nontemporal_store(cn, cout + (size_t)(g0 + j) * 64 + lane);
        nom += s_qh[lr] * cn;
    }
    s_nom[wv][lane] = nom;
    __syncthreads();

    if (t < 64) {
        const f32x4 sum = s_nom[0][t] + s_nom[1][t] + s_nom[2][t] + s_nom[3][t];
        ((f32x4*)(ws_w + PS))[(size_t)blk * 64 + t] = sum;
    }
}

// ---------------------------------------------------------------------------
// Kernel C (512 blocks x 64): reduce stripe partials, h_tilde -> LayerNorm.
// ---------------------------------------------------------------------------
__global__ __launch_bounds__(64) void ln_kernel(
    const float* __restrict__ ln_s, const float* __restrict__ ws,
    float* __restrict__ out)
{
    const int blk  = blockIdx.x;    // b*8 + h
    const int h    = blk & 7;
    const int lane = threadIdx.x;

    const f32x4* pp = (const f32x4*)(ws + PS);
    f32x4 nt = {0.f, 0.f, 0.f, 0.f};
#pragma unroll
    for (int s = 0; s < 4; ++s)
        nt += pp[((size_t)blk * 4 + s) * 64 + lane];

    const float rden = 1.f / ws[blk * 4 + 3];
    const f32x4 ht   = nt * rden;

    float s = ht[0] + ht[1] + ht[2] + ht[3];
#pragma unroll
    for (int o = 32; o > 0; o >>= 1) s += __shfl_down(s, o, 64);
    s = __shfl(s, 0, 64);
    const float mu = s * (1.f / 256.f);

    const f32x4 d = ht - mu;
    float vs = d[0] * d[0] + d[1] * d[1] + d[2] * d[2] + d[3] * d[3];
#pragma unroll
    for (int o = 32; o > 0; o >>= 1) vs += __shfl_down(vs, o, 64);
    vs = __shfl(vs, 0, 64);
    const float rs = rsqrtf(vs * (1.f / 256.f) + 1e-6f);

    const f32x4 lns = ((const f32x4*)(ln_s + h * HDd))[lane];
    ((f32x4*)(out + H_OFF + (size_t)blk * HDd))[lane] = d * rs * lns;
}

extern "C" void kernel_launch(void* const* d_in, const int* in_sizes, int n_in,
                              void* d_out, int out_size, void* d_ws, size_t ws_size,
                              hipStream_t stream)
{
    const float* q    = (const float*)d_in[0];
    const float* k    = (const float*)d_in[1];
    const float* v    = (const float*)d_in[2];
    const float* c    = (const float*)d_in[3];
    const float* n    = (const float*)d_in[4];
    const float* m    = (const float*)d_in[5];
    const float* wi_k = (const float*)d_in[6];
    const float* wi_b = (const float*)d_in[7];
    const float* wf_k = (const float*)d_in[8];
    const float* wf_b = (const float*)d_in[9];
    const float* ln_s = (const float*)d_in[10];
    float* out = (float*)d_out;
    float* ws  = (float*)d_ws;

    gates_kernel<<<dim3(Bb), dim3(256), 0, stream>>>(
        q, k, v, n, m, wi_k, wi_b, wf_k, wf_b, ws, out);
    stream_kernel<<<dim3(Bb * NHh * 4), dim3(256), 0, stream>>>(
        q, k, v, c, ws, ws, out);
    ln_kernel<<<dim3(Bb * NHh), dim3(64), 0, stream>>>(ln_s, ws, out);
}

// Round 10
// 262.370 us; speedup vs baseline: 1.0432x; 1.0432x over previous
//
#include <hip/hip_runtime.h>
#include <math.h>

typedef float f32x4 __attribute__((ext_vector_type(4)));

// Problem constants: B=64, H=2048, NH=8, HD=256
constexpr int Bb  = 64;
constexpr int Hh  = 2048;
constexpr int NHh = 8;
constexpr int HDd = 256;

// Output flat offsets (c_new, n_new, m_new, h_norm), all f32
constexpr size_t C_OFF = 0;
constexpr size_t N_OFF = (size_t)Bb * NHh * HDd * HDd;            // 33554432
constexpr size_t M_OFF = N_OFF + (size_t)Bb * NHh * HDd;          // 33685504
constexpr size_t H_OFF = M_OFF + (size_t)Bb * NHh;                // 33686016

// ---------------------------------------------------------------------------
// Kernel A (64 blocks x 256): gates + n_new + denominator, and zeroes the
// h_norm region (reused as the atomic nom accumulator for kernel B).
// ws per (b,h): [4*blk +0]=f', +1=i', +2=m_new, +3=denom
// ---------------------------------------------------------------------------
__global__ __launch_bounds__(256) void gates_kernel(
    const float* __restrict__ q, const float* __restrict__ k,
    const float* __restrict__ v, const float* __restrict__ n_in,
    const float* __restrict__ m_in,
    const float* __restrict__ wi_k, const float* __restrict__ wi_b,
    const float* __restrict__ wf_k, const float* __restrict__ wf_b,
    float* __restrict__ ws, float* __restrict__ out)
{
    const int b    = blockIdx.x;
    const int t    = threadIdx.x;
    const int lane = t & 63;
    const int wv   = t >> 6;

    // zero nom accumulator region for this batch (2048 floats, 8 per thread)
    {
        f32x4 z = {0.f, 0.f, 0.f, 0.f};
        f32x4* zp = (f32x4*)(out + H_OFF + (size_t)b * Hh) + t * 2;
        zp[0] = z; zp[1] = z;
    }

    float ai[8], af[8];
#pragma unroll
    for (int i = 0; i < 8; ++i) { ai[i] = 0.f; af[i] = 0.f; }

#pragma unroll 4
    for (int j = 0; j < 24; ++j) {
        const int r = t + 256 * j;
        float x;
        if (r < Hh)            x = q[b * Hh + r];
        else if (r < 2 * Hh)   x = k[b * Hh + r - Hh];
        else                   x = v[b * Hh + r - 2 * Hh];

        const f32x4 wa = *(const f32x4*)(wi_k + (size_t)r * 8);
        const f32x4 wb = *(const f32x4*)(wi_k + (size_t)r * 8 + 4);
        ai[0] = fmaf(x, wa[0], ai[0]); ai[1] = fmaf(x, wa[1], ai[1]);
        ai[2] = fmaf(x, wa[2], ai[2]); ai[3] = fmaf(x, wa[3], ai[3]);
        ai[4] = fmaf(x, wb[0], ai[4]); ai[5] = fmaf(x, wb[1], ai[5]);
        ai[6] = fmaf(x, wb[2], ai[6]); ai[7] = fmaf(x, wb[3], ai[7]);

        const f32x4 fa = *(const f32x4*)(wf_k + (size_t)r * 8);
        const f32x4 fb = *(const f32x4*)(wf_k + (size_t)r * 8 + 4);
        af[0] = fmaf(x, fa[0], af[0]); af[1] = fmaf(x, fa[1], af[1]);
        af[2] = fmaf(x, fa[2], af[2]); af[3] = fmaf(x, fa[3], af[3]);
        af[4] = fmaf(x, fb[0], af[4]); af[5] = fmaf(x, fb[1], af[5]);
        af[6] = fmaf(x, fb[2], af[6]); af[7] = fmaf(x, fb[3], af[7]);
    }

#pragma unroll
    for (int i = 0; i < 8; ++i) {
#pragma unroll
        for (int o = 32; o > 0; o >>= 1) {
            ai[i] += __shfl_down(ai[i], o, 64);
            af[i] += __shfl_down(af[i], o, 64);
        }
    }

    __shared__ float s_part[4][16];
    __shared__ float s_g[8][3];     // f', i', m_new per head
    if (lane == 0) {
#pragma unroll
        for (int i = 0; i < 8; ++i) {
            s_part[wv][i]     = ai[i];
            s_part[wv][8 + i] = af[i];
        }
    }
    __syncthreads();

    if (t < 8) {
        const int h = t;
        const float it = s_part[0][h] + s_part[1][h] + s_part[2][h] + s_part[3][h]
                         + wi_b[h];
        const float ft = s_part[0][8 + h] + s_part[1][8 + h] + s_part[2][8 + h]
                         + s_part[3][8 + h] + wf_b[h];
        const float logf_ = -(fmaxf(-ft, 0.f) + log1pf(expf(-fabsf(ft))));
        const float m_old = m_in[b * NHh + h];
        const float m_new = fmaxf(logf_ + m_old, it);
        const float fp    = expf(logf_ + m_old - m_new);
        const float ip    = expf(it - m_new);
        const int blk = b * NHh + h;
        s_g[h][0] = fp; s_g[h][1] = ip; s_g[h][2] = m_new;
        ws[blk * 4 + 0] = fp;
        ws[blk * 4 + 1] = ip;
        ws[blk * 4 + 2] = m_new;
        out[M_OFF + blk] = m_new;
    }
    __syncthreads();

    // n_new (8 heads x 256) + per-head denominator dot
    float pd[8];
#pragma unroll
    for (int h = 0; h < 8; ++h) {
        const float kv = k[b * Hh + h * HDd + t] * 0.0625f;   // 1/sqrt(256)
        const float nn = fmaf(s_g[h][0], n_in[((size_t)b * 8 + h) * HDd + t],
                              s_g[h][1] * kv);
        out[N_OFF + ((size_t)b * 8 + h) * HDd + t] = nn;
        pd[h] = q[b * Hh + h * HDd + t] * nn;
    }
#pragma unroll
    for (int h = 0; h < 8; ++h)
#pragma unroll
        for (int o = 32; o > 0; o >>= 1) pd[h] += __shfl_down(pd[h], o, 64);

    __shared__ float s_dp[4][8];
    if (lane == 0) {
#pragma unroll
        for (int h = 0; h < 8; ++h) s_dp[wv][h] = pd[h];
    }
    __syncthreads();
    if (t < 8) {
        const float dd = s_dp[0][t] + s_dp[1][t] + s_dp[2][t] + s_dp[3][t];
        ws[(b * 8 + t) * 4 + 3] = fmaxf(fabsf(dd), expf(-s_g[t][2])) + 1e-6f;
    }
}

// ---------------------------------------------------------------------------
// Kernel B (4096 blocks x 256): copy-shaped c-stream — ROUND-4 best-measured
// config, verbatim. Block = 32-row stripe of one (b,h) tile. Wave wv owns 8
// consecutive rows; lane owns float4-column. 8 fully-unrolled nontemporal
// load/store pairs per thread; qh^T c_new partials atomicAdd'ed into
// out[H_OFF + tile*256 + ...] (pre-zeroed by kernel A).
// ---------------------------------------------------------------------------
__global__ __launch_bounds__(256) void stream_kernel(
    const float* __restrict__ q, const float* __restrict__ k,
    const float* __restrict__ v, const float* __restrict__ c_in,
    const float* __restrict__ ws, float* __restrict__ out)
{
    const int blk  = blockIdx.x;
    const int tile = blk >> 3;      // b*8 + h
    const int s    = blk & 7;       // stripe
    const int b    = tile >> 3;
    const int h    = tile & 7;
    const int t    = threadIdx.x;
    const int lane = t & 63;
    const int wv   = t >> 6;

    __shared__ float s_kh[32];
    __shared__ float s_qh[32];
    __shared__ f32x4 s_nom[4][64];

    if (t < 32) {
        const int r = s * 32 + t;
        s_kh[t] = k[b * Hh + h * HDd + r] * 0.0625f;
        s_qh[t] = q[b * Hh + h * HDd + r];
    }
    const float fp  = ws[tile * 4 + 0];
    const float ip  = ws[tile * 4 + 1];
    const f32x4 vh4 = ((const f32x4*)(v + b * Hh + h * HDd))[lane];
    __syncthreads();

    const size_t cbase = (size_t)tile * (HDd * HDd);
    const f32x4* cin   = (const f32x4*)(c_in + cbase);
    f32x4*       cout  = (f32x4*)(out + C_OFF + cbase);
    f32x4 nom = {0.f, 0.f, 0.f, 0.f};
    const int rb = wv * 8;

#pragma unroll
    for (int j = 0; j < 8; ++j) {
        const int   r   = rb + j;                 // row within stripe
        const float a   = ip * s_kh[r];
        const float qh1 = s_qh[r];
        const int   idx = (s * 32 + r) * 64 + lane;
        f32x4 cv = __builtin_nontemporal_load(cin + idx);
        f32x4 cn = fp * cv + a * vh4;
        __builtin_nontemporal_store(cn, cout + idx);
        nom += qh1 * cn;
    }
    s_nom[wv][lane] = nom;
    __syncthreads();

    if (t < 64) {
        f32x4 sum = s_nom[0][t] + s_nom[1][t] + s_nom[2][t] + s_nom[3][t];
        float* dst = out + H_OFF + (size_t)tile * HDd + t * 4;
        atomicAdd(dst + 0, sum[0]);
        atomicAdd(dst + 1, sum[1]);
        atomicAdd(dst + 2, sum[2]);
        atomicAdd(dst + 3, sum[3]);
    }
}

// ---------------------------------------------------------------------------
// Kernel C (512 blocks x 64): finish h_tilde -> LayerNorm, in place.
// ---------------------------------------------------------------------------
__global__ __launch_bounds__(64) void ln_kernel(
    const float* __restrict__ ln_s, const float* __restrict__ ws,
    float* __restrict__ out)
{
    const int blk  = blockIdx.x;    // b*8 + h
    const int h    = blk & 7;
    const int lane = threadIdx.x;

    float* hp = out + H_OFF + (size_t)blk * HDd;
    const f32x4 nt   = ((const f32x4*)hp)[lane];
    const float rden = 1.f / ws[blk * 4 + 3];
    f32x4 ht = nt * rden;

    float s = ht[0] + ht[1] + ht[2] + ht[3];
#pragma unroll
    for (int o = 32; o > 0; o >>= 1) s += __shfl_down(s, o, 64);
    s = __shfl(s, 0, 64);
    const float mu = s * (1.f / 256.f);

    const f32x4 d = ht - mu;
    float vs = d[0] * d[0] + d[1] * d[1] + d[2] * d[2] + d[3] * d[3];
#pragma unroll
    for (int o = 32; o > 0; o >>= 1) vs += __shfl_down(vs, o, 64);
    vs = __shfl(vs, 0, 64);
    const float rs = rsqrtf(vs * (1.f / 256.f) + 1e-6f);

    const f32x4 lns = ((const f32x4*)(ln_s + h * HDd))[lane];
    ((f32x4*)hp)[lane] = d * rs * lns;
}

extern "C" void kernel_launch(void* const* d_in, const int* in_sizes, int n_in,
                              void* d_out, int out_size, void* d_ws, size_t ws_size,
                              hipStream_t stream)
{
    const float* q    = (const float*)d_in[0];
    const float* k    = (const float*)d_in[1];
    const float* v    = (const float*)d_in[2];
    const float* c    = (const float*)d_in[3];
    const float* n    = (const float*)d_in[4];
    const float* m    = (const float*)d_in[5];
    const float* wi_k = (const float*)d_in[6];
    const float* wi_b = (const float*)d_in[7];
    const float* wf_k = (const float*)d_in[8];
    const float* wf_b = (const float*)d_in[9];
    const float* ln_s = (const float*)d_in[10];
    float* out = (float*)d_out;
    float* ws  = (float*)d_ws;

    gates_kernel<<<dim3(Bb), dim3(256), 0, stream>>>(
        q, k, v, n, m, wi_k, wi_b, wf_k, wf_b, ws, out);
    stream_kernel<<<dim3(Bb * NHh * 8), dim3(256), 0, stream>>>(
        q, k, v, c, ws, out);
    ln_kernel<<<dim3(Bb * NHh), dim3(64), 0, stream>>>(ln_s, ws, out);
}